// Round 2
// baseline (587.712 us; speedup 1.0000x reference)
//
#include <hip/hip_runtime.h>
#include <hip/hip_bf16.h>

#define NB 4
#define NH 16
#define NS 1024
#define ND 64
#define NBH (NB * NH)
#define NELEM ((size_t)NBH * NS * ND)   // 4,194,304

typedef __bf16 bf16x8 __attribute__((ext_vector_type(8)));
typedef float f32x4 __attribute__((ext_vector_type(4)));
typedef unsigned short u16x8 __attribute__((ext_vector_type(8)));
typedef unsigned short u16x4 __attribute__((ext_vector_type(4)));

// ---------------- pre-pass kernels (write bf16 planes into d_ws) ----------------

// hi/lo bf16 split of a f32 tensor (optionally pre-scaled). 4 elems/thread.
__global__ __launch_bounds__(256) void conv_hilo(const float* __restrict__ src,
                                                 unsigned short* __restrict__ hi,
                                                 unsigned short* __restrict__ lo,
                                                 float scale, int n4) {
    int i = blockIdx.x * 256 + threadIdx.x;
    if (i >= n4) return;
    f32x4 x = ((const f32x4*)src)[i];
    u16x4 h, l;
#pragma unroll
    for (int j = 0; j < 4; ++j) {
        float xs = x[j] * scale;
        __bf16 hb = (__bf16)xs;
        h[j] = __builtin_bit_cast(unsigned short, hb);
        l[j] = __builtin_bit_cast(unsigned short, (__bf16)(xs - (float)hb));
    }
    ((u16x4*)hi)[i] = h;
    ((u16x4*)lo)[i] = l;
}

// V[bh][k][d] f32  ->  Vt[bh][d][k] bf16 (transpose so PV B-fragments are contiguous)
__global__ __launch_bounds__(256) void conv_vt(const float* __restrict__ V,
                                               unsigned short* __restrict__ Vt) {
    int i = blockIdx.x * 256 + threadIdx.x;   // 64 bh * 64 kb * 64 d = 262144
    int bh = i >> 12;
    int kb = (i >> 6) & 63;
    int d  = i & 63;
    const float* vp = V + ((size_t)(bh * NS + kb * 16)) * ND + d;   // coalesced over d
    unsigned short* op = Vt + ((size_t)(bh * ND + d)) * NS + kb * 16;
    u16x8 o0, o1;
#pragma unroll
    for (int r = 0; r < 8; ++r) o0[r] = __builtin_bit_cast(unsigned short, (__bf16)vp[r * ND]);
#pragma unroll
    for (int r = 0; r < 8; ++r) o1[r] = __builtin_bit_cast(unsigned short, (__bf16)vp[(r + 8) * ND]);
    *(u16x8*)op = o0;
    *(u16x8*)(op + 8) = o1;
}

// ---------------- main fused kernel (pre-converted operands) ----------------
// Block: 256 thr = 4 waves; one (b,h) + 16-query tile; wave w owns keys [w*256, w*256+256).
// Swapped QK^T: mfma(A=K, B=Q) -> lane holds (query = lane&15, keys = (lane>>4)*4 + r).
__global__ __launch_bounds__(256) void fused_attn_pre(
    const unsigned short* __restrict__ Qhi, const unsigned short* __restrict__ Qlo,
    const unsigned short* __restrict__ Khi, const unsigned short* __restrict__ Klo,
    const unsigned short* __restrict__ Vt,
    const int* __restrict__ mask, const float* __restrict__ adj, const float* __restrict__ dist,
    float* __restrict__ out_g, float* __restrict__ attn_g)
{
    const int tid  = (int)threadIdx.x;
    const int lane = tid & 63;
    const int wid  = tid >> 6;
    const int qi   = lane & 15;
    const int g    = lane >> 4;

    int bid = (int)blockIdx.x;
    bid = (bid & 7) * (NBH * 64 / 8) + (bid >> 3);   // XCD swizzle (bijective: 4096 % 8 == 0)
    const int qt = bid & 63;
    const int bh = bid >> 6;
    const int b  = bh >> 4;

    // LDS: Plds (32 KB, per-wave 8 KB P tiles) unioned with outp (17.4 KB, used after PV).
    __shared__ __align__(16) unsigned char smem[4 * 16 * 256 * 2 + 512];
    unsigned short* Plds = (unsigned short*)smem;
    float* red_m = (float*)(smem + 32768);          // [4][16]
    float* red_l = red_m + 64;                      // [4][16]
    typedef float outp_t[16][68];                   // +4 pad
    outp_t* outp = (outp_t*)smem;                   // union with Plds

    const int qglob = qt * 16 + qi;
    const int kw    = wid * 256;

    // ---- Q fragments (B operand), pre-scaled by 1/8 in conv pass
    bf16x8 qh[2], ql[2];
    {
        const size_t qo = ((size_t)(bh * NS + qglob)) * ND + g * 8;
        qh[0] = __builtin_bit_cast(bf16x8, *(const u16x8*)(Qhi + qo));
        qh[1] = __builtin_bit_cast(bf16x8, *(const u16x8*)(Qhi + qo + 32));
        ql[0] = __builtin_bit_cast(bf16x8, *(const u16x8*)(Qlo + qo));
        ql[1] = __builtin_bit_cast(bf16x8, *(const u16x8*)(Qlo + qo + 32));
    }

    // ---- QK^T with hi/lo compensation (3 MFMAs per 32-d chunk)
    f32x4 acc[16];
    {
        const f32x4 z = {0.f, 0.f, 0.f, 0.f};
#pragma unroll
        for (int t = 0; t < 16; ++t) acc[t] = z;
    }
#pragma unroll
    for (int t = 0; t < 16; ++t) {
        const size_t ko = ((size_t)(bh * NS + kw + t * 16 + qi)) * ND + g * 8;
#pragma unroll
        for (int c = 0; c < 2; ++c) {
            bf16x8 kh = __builtin_bit_cast(bf16x8, *(const u16x8*)(Khi + ko + c * 32));
            bf16x8 kl = __builtin_bit_cast(bf16x8, *(const u16x8*)(Klo + ko + c * 32));
            acc[t] = __builtin_amdgcn_mfma_f32_16x16x32_bf16(kh, qh[c], acc[t], 0, 0, 0);
            acc[t] = __builtin_amdgcn_mfma_f32_16x16x32_bf16(kl, qh[c], acc[t], 0, 0, 0);
            acc[t] = __builtin_amdgcn_mfma_f32_16x16x32_bf16(kh, ql[c], acc[t], 0, 0, 0);
        }
    }

    // ---- elementwise: relu * rescaled + adj, mask -> -1e9
    const float* adjR  = adj  + ((size_t)(b * NS + qglob)) * NS;
    const float* distR = dist + ((size_t)(b * NS + qglob)) * NS;
    const int*   maskR = mask + b * NS;
    const float  CE = 3.7182817f;  // 1 + e

#pragma unroll
    for (int t = 0; t < 16; ++t) {
        const int k0 = kw + t * 16 + g * 4;
        f32x4 a4 = *(const f32x4*)(adjR + k0);
        f32x4 d4 = *(const f32x4*)(distR + k0);
        int4  m4 = *(const int4*)(maskR + k0);
        int   mm[4] = {m4.x, m4.y, m4.z, m4.w};
#pragma unroll
        for (int r = 0; r < 4; ++r) {
            float s = fmaxf(acc[t][r], 0.f);
            float resc = CE * __builtin_amdgcn_rcpf(1.f + __expf(1.f - d4[r]));
            s = s * resc + a4[r];
            acc[t][r] = (mm[r] == 0) ? -1.0e9f : s;
        }
    }

    // ---- softmax over full 1024-key row
    float m = -3.0e38f;
#pragma unroll
    for (int t = 0; t < 16; ++t)
#pragma unroll
        for (int r = 0; r < 4; ++r) m = fmaxf(m, acc[t][r]);
    m = fmaxf(m, __shfl_xor(m, 16, 64));
    m = fmaxf(m, __shfl_xor(m, 32, 64));
    if (g == 0) red_m[wid * 16 + qi] = m;
    __syncthreads();
    const float mf = fmaxf(fmaxf(red_m[qi], red_m[16 + qi]),
                           fmaxf(red_m[32 + qi], red_m[48 + qi]));

    float l = 0.f;
#pragma unroll
    for (int t = 0; t < 16; ++t)
#pragma unroll
        for (int r = 0; r < 4; ++r) {
            float e = __expf(acc[t][r] - mf);
            acc[t][r] = e;
            l += e;
        }
    l += __shfl_xor(l, 16, 64);
    l += __shfl_xor(l, 32, 64);
    if (g == 0) red_l[wid * 16 + qi] = l;
    __syncthreads();
    const float lf = red_l[qi] + red_l[16 + qi] + red_l[32 + qi] + red_l[48 + qi];
    const float inv = __builtin_amdgcn_rcpf(lf);

    // ---- write attn (f32, nontemporal) + pack P to LDS (bf16, 16B-chunk XOR swizzle)
    float* attnR = attn_g + ((size_t)(bh * NS + qglob)) * NS;
    unsigned short* Pw = Plds + wid * (16 * 256);
#pragma unroll
    for (int t = 0; t < 16; ++t) {
        const int kloc = t * 16 + g * 4;
        f32x4 e4;
#pragma unroll
        for (int r = 0; r < 4; ++r) e4[r] = acc[t][r] * inv;
        __builtin_nontemporal_store(e4, (f32x4*)(attnR + kw + kloc));

        unsigned int p01 = ((unsigned int)__builtin_bit_cast(unsigned short, (__bf16)e4[0]))
                         | ((unsigned int)__builtin_bit_cast(unsigned short, (__bf16)e4[1]) << 16);
        unsigned int p23 = ((unsigned int)__builtin_bit_cast(unsigned short, (__bf16)e4[2]))
                         | ((unsigned int)__builtin_bit_cast(unsigned short, (__bf16)e4[3]) << 16);
        const int u = kloc >> 2;          // 8B unit within row
        const int c = u >> 1;             // 16B chunk 0..31
        unsigned long long pk = (unsigned long long)p01 | ((unsigned long long)p23 << 32);
        *(unsigned long long*)((char*)Pw + qi * 512 + ((c ^ (qi & 7)) << 4) + (u & 1) * 8) = pk;
    }
    __syncthreads();

    // ---- PV: A = P (LDS), B = V^T (b128 global loads, L2-resident)
    f32x4 o[4];
    {
        const f32x4 z = {0.f, 0.f, 0.f, 0.f};
#pragma unroll
        for (int dt = 0; dt < 4; ++dt) o[dt] = z;
    }
    const unsigned short* vtb = Vt + ((size_t)bh * ND) * NS;
#pragma unroll
    for (int j = 0; j < 8; ++j) {                 // 32-key chunks
        const int c = j * 4 + g;
        const u16x8 praw = *(const u16x8*)((const char*)Pw + qi * 512 + ((c ^ (qi & 7)) << 4));
        const bf16x8 pa = __builtin_bit_cast(bf16x8, praw);
#pragma unroll
        for (int dt = 0; dt < 4; ++dt) {          // 16-wide d tiles
            const bf16x8 vb = __builtin_bit_cast(bf16x8,
                *(const u16x8*)(vtb + (size_t)(dt * 16 + qi) * NS + kw + j * 32 + g * 8));
            o[dt] = __builtin_amdgcn_mfma_f32_16x16x32_bf16(pa, vb, o[dt], 0, 0, 0);
        }
    }
    __syncthreads();   // Plds dead; outp (union) comes live

    // ---- cross-wave reduce of k-split partials, store out
#pragma unroll
    for (int dt = 0; dt < 4; ++dt)
#pragma unroll
        for (int r = 0; r < 4; ++r)
            outp[wid][g * 4 + r][dt * 16 + qi] = o[dt][r];
    __syncthreads();
    {
        const int qrow = tid >> 4;
        const int d0   = (tid & 15) * 4;
        f32x4 s = *(const f32x4*)(&outp[0][qrow][d0]);
#pragma unroll
        for (int w = 1; w < 4; ++w) s += *(const f32x4*)(&outp[w][qrow][d0]);
        __builtin_nontemporal_store(s, (f32x4*)(out_g + ((size_t)(bh * NS + qt * 16 + qrow)) * ND + d0));
    }
}

// ---------------- fallback (self-contained, from round 1) ----------------
__global__ __launch_bounds__(256) void fused_attn_kernel(
    const float* __restrict__ Q, const float* __restrict__ K, const float* __restrict__ V,
    const int* __restrict__ mask, const float* __restrict__ adj, const float* __restrict__ dist,
    float* __restrict__ out_g, float* __restrict__ attn_g)
{
    const int tid  = (int)threadIdx.x;
    const int lane = tid & 63;
    const int wid  = tid >> 6;
    const int qi   = lane & 15;
    const int g    = lane >> 4;

    const int bid = (int)blockIdx.x;
    const int qt  = bid & 63;
    const int bh  = bid >> 6;
    const int b   = bh >> 4;

    __shared__ __align__(16) unsigned short Plds[4][16 * 256];
    __shared__ __align__(16) float outp[4][16][68];
    __shared__ float red_m[4][16];
    __shared__ float red_l[4][16];

    const int qglob = qt * 16 + qi;
    const int kw    = wid * 256;

    bf16x8 qh[2], ql[2];
    {
        const float* qp = Q + (bh * NS + qglob) * ND + g * 8;
#pragma unroll
        for (int c = 0; c < 2; ++c) {
            f32x4 f0 = *(const f32x4*)(qp + c * 32);
            f32x4 f1 = *(const f32x4*)(qp + c * 32 + 4);
#pragma unroll
            for (int j = 0; j < 4; ++j) {
                float xh = f0[j] * 0.125f;
                __bf16 hb = (__bf16)xh;
                qh[c][j] = hb; ql[c][j] = (__bf16)(xh - (float)hb);
                float xl = f1[j] * 0.125f;
                __bf16 hb2 = (__bf16)xl;
                qh[c][j + 4] = hb2; ql[c][j + 4] = (__bf16)(xl - (float)hb2);
            }
        }
    }

    f32x4 acc[16];
    {
        const f32x4 z = {0.f, 0.f, 0.f, 0.f};
#pragma unroll
        for (int t = 0; t < 16; ++t) acc[t] = z;
    }
#pragma unroll
    for (int t = 0; t < 16; ++t) {
        const float* kp = K + (bh * NS + kw + t * 16 + qi) * ND + g * 8;
#pragma unroll
        for (int c = 0; c < 2; ++c) {
            f32x4 f0 = *(const f32x4*)(kp + c * 32);
            f32x4 f1 = *(const f32x4*)(kp + c * 32 + 4);
            bf16x8 kh, kl;
#pragma unroll
            for (int j = 0; j < 4; ++j) {
                __bf16 hb = (__bf16)f0[j];
                kh[j] = hb; kl[j] = (__bf16)(f0[j] - (float)hb);
                __bf16 hb2 = (__bf16)f1[j];
                kh[j + 4] = hb2; kl[j + 4] = (__bf16)(f1[j] - (float)hb2);
            }
            acc[t] = __builtin_amdgcn_mfma_f32_16x16x32_bf16(kh, qh[c], acc[t], 0, 0, 0);
            acc[t] = __builtin_amdgcn_mfma_f32_16x16x32_bf16(kl, qh[c], acc[t], 0, 0, 0);
            acc[t] = __builtin_amdgcn_mfma_f32_16x16x32_bf16(kh, ql[c], acc[t], 0, 0, 0);
        }
    }

    const float* adjR  = adj  + (b * NS + qglob) * (size_t)NS;
    const float* distR = dist + (b * NS + qglob) * (size_t)NS;
    const int*   maskR = mask + b * NS;
    const float  CE = 3.7182817f;

#pragma unroll
    for (int t = 0; t < 16; ++t) {
        const int k0 = kw + t * 16 + g * 4;
        f32x4 a4 = *(const f32x4*)(adjR + k0);
        f32x4 d4 = *(const f32x4*)(distR + k0);
        int4  m4 = *(const int4*)(maskR + k0);
        int   mm[4] = {m4.x, m4.y, m4.z, m4.w};
#pragma unroll
        for (int r = 0; r < 4; ++r) {
            float s = fmaxf(acc[t][r], 0.f);
            float resc = CE * __builtin_amdgcn_rcpf(1.f + __expf(1.f - d4[r]));
            s = s * resc + a4[r];
            acc[t][r] = (mm[r] == 0) ? -1.0e9f : s;
        }
    }

    float m = -3.0e38f;
#pragma unroll
    for (int t = 0; t < 16; ++t)
#pragma unroll
        for (int r = 0; r < 4; ++r) m = fmaxf(m, acc[t][r]);
    m = fmaxf(m, __shfl_xor(m, 16, 64));
    m = fmaxf(m, __shfl_xor(m, 32, 64));
    if (g == 0) red_m[wid][qi] = m;
    __syncthreads();
    const float mf = fmaxf(fmaxf(red_m[0][qi], red_m[1][qi]),
                           fmaxf(red_m[2][qi], red_m[3][qi]));

    float l = 0.f;
#pragma unroll
    for (int t = 0; t < 16; ++t)
#pragma unroll
        for (int r = 0; r < 4; ++r) {
            float e = __expf(acc[t][r] - mf);
            acc[t][r] = e;
            l += e;
        }
    l += __shfl_xor(l, 16, 64);
    l += __shfl_xor(l, 32, 64);
    if (g == 0) red_l[wid][qi] = l;
    __syncthreads();
    const float lf = red_l[0][qi] + red_l[1][qi] + red_l[2][qi] + red_l[3][qi];
    const float inv = __builtin_amdgcn_rcpf(lf);

    float* attnR = attn_g + (bh * NS + qglob) * (size_t)NS;
    unsigned short* Pw = &Plds[wid][0];
#pragma unroll
    for (int t = 0; t < 16; ++t) {
        const int kloc = t * 16 + g * 4;
        f32x4 e4;
#pragma unroll
        for (int r = 0; r < 4; ++r) e4[r] = acc[t][r] * inv;
        __builtin_nontemporal_store(e4, (f32x4*)(attnR + kw + kloc));

        unsigned int p01 = ((unsigned int)__builtin_bit_cast(unsigned short, (__bf16)e4[0]))
                         | ((unsigned int)__builtin_bit_cast(unsigned short, (__bf16)e4[1]) << 16);
        unsigned int p23 = ((unsigned int)__builtin_bit_cast(unsigned short, (__bf16)e4[2]))
                         | ((unsigned int)__builtin_bit_cast(unsigned short, (__bf16)e4[3]) << 16);
        const int u = kloc >> 2;
        const int c = u >> 1;
        unsigned long long pk = (unsigned long long)p01 | ((unsigned long long)p23 << 32);
        *(unsigned long long*)((char*)Pw + qi * 512 + ((c ^ (qi & 7)) << 4) + (u & 1) * 8) = pk;
    }
    __syncthreads();

    f32x4 o[4];
    {
        const f32x4 z = {0.f, 0.f, 0.f, 0.f};
#pragma unroll
        for (int dt = 0; dt < 4; ++dt) o[dt] = z;
    }
    const float* vbase = V + (bh * NS + kw) * (size_t)ND;
#pragma unroll
    for (int j = 0; j < 8; ++j) {
        const int c = j * 4 + g;
        const u16x8 praw = *(const u16x8*)((const char*)Pw + qi * 512 + ((c ^ (qi & 7)) << 4));
        const bf16x8 pa = __builtin_bit_cast(bf16x8, praw);
        const float* vp0 = vbase + (j * 32 + g * 8) * ND + qi;
#pragma unroll
        for (int dt = 0; dt < 4; ++dt) {
            bf16x8 vb;
            const float* vp = vp0 + dt * 16;
#pragma unroll
            for (int r = 0; r < 8; ++r) vb[r] = (__bf16)vp[r * ND];
            o[dt] = __builtin_amdgcn_mfma_f32_16x16x32_bf16(pa, vb, o[dt], 0, 0, 0);
        }
    }

#pragma unroll
    for (int dt = 0; dt < 4; ++dt)
#pragma unroll
        for (int r = 0; r < 4; ++r)
            outp[wid][g * 4 + r][dt * 16 + qi] = o[dt][r];
    __syncthreads();
    {
        const int qrow = tid >> 4;
        const int d0   = (tid & 15) * 4;
        f32x4 s = *(const f32x4*)(&outp[0][qrow][d0]);
#pragma unroll
        for (int w = 1; w < 4; ++w) s += *(const f32x4*)(&outp[w][qrow][d0]);
        __builtin_nontemporal_store(s, (f32x4*)(out_g + (bh * NS + qt * 16 + qrow) * (size_t)ND + d0));
    }
}

extern "C" void kernel_launch(void* const* d_in, const int* in_sizes, int n_in,
                              void* d_out, int out_size, void* d_ws, size_t ws_size,
                              hipStream_t stream) {
    const float* Q    = (const float*)d_in[0];
    const float* K    = (const float*)d_in[1];
    const float* V    = (const float*)d_in[2];
    const int*   mask = (const int*)d_in[3];
    const float* adj  = (const float*)d_in[4];
    const float* dist = (const float*)d_in[5];
    float* out  = (float*)d_out;
    float* attn = out + NELEM;   // outputs concatenated: (output, attn)

    const size_t need = NELEM * 2 * 5;   // Qhi,Qlo,Khi,Klo,Vt bf16 planes = 40 MB
    if (ws_size >= need) {
        unsigned short* Qhi = (unsigned short*)d_ws;
        unsigned short* Qlo = Qhi + NELEM;
        unsigned short* Khi = Qlo + NELEM;
        unsigned short* Klo = Khi + NELEM;
        unsigned short* Vt  = Klo + NELEM;
        const int n4 = (int)(NELEM / 4);
        conv_hilo<<<dim3(n4 / 256), 256, 0, stream>>>(Q, Qhi, Qlo, 0.125f, n4);
        conv_hilo<<<dim3(n4 / 256), 256, 0, stream>>>(K, Khi, Klo, 1.0f, n4);
        conv_vt<<<dim3(NBH * ND * (NS / 16) / 256), 256, 0, stream>>>(V, Vt);
        fused_attn_pre<<<dim3(NBH * 64), 256, 0, stream>>>(Qhi, Qlo, Khi, Klo, Vt,
                                                           mask, adj, dist, out, attn);
    } else {
        fused_attn_kernel<<<dim3(NBH * 64), 256, 0, stream>>>(Q, K, V, mask, adj, dist, out, attn);
    }
}

// Round 3
// 558.088 us; speedup vs baseline: 1.0531x; 1.0531x over previous
//
#include <hip/hip_runtime.h>
#include <hip/hip_bf16.h>

#define NB 4
#define NH 16
#define NS 1024
#define ND 64
#define NBH (NB * NH)
#define NELEM ((size_t)NBH * NS * ND)   // 4,194,304

typedef __bf16 bf16x8 __attribute__((ext_vector_type(8)));
typedef float f32x4 __attribute__((ext_vector_type(4)));
typedef unsigned short u16x8 __attribute__((ext_vector_type(8)));
typedef unsigned short u16x4 __attribute__((ext_vector_type(4)));

// ---------------- pre-pass kernels (write bf16 planes into d_ws) ----------------

__global__ __launch_bounds__(256) void conv_hilo(const float* __restrict__ src,
                                                 unsigned short* __restrict__ hi,
                                                 unsigned short* __restrict__ lo,
                                                 float scale, int n4) {
    int i = blockIdx.x * 256 + threadIdx.x;
    if (i >= n4) return;
    f32x4 x = ((const f32x4*)src)[i];
    u16x4 h, l;
#pragma unroll
    for (int j = 0; j < 4; ++j) {
        float xs = x[j] * scale;
        __bf16 hb = (__bf16)xs;
        h[j] = __builtin_bit_cast(unsigned short, hb);
        l[j] = __builtin_bit_cast(unsigned short, (__bf16)(xs - (float)hb));
    }
    ((u16x4*)hi)[i] = h;
    ((u16x4*)lo)[i] = l;
}

// V[bh][k][d] f32 -> Vt[bh][d][k] bf16
__global__ __launch_bounds__(256) void conv_vt(const float* __restrict__ V,
                                               unsigned short* __restrict__ Vt) {
    int i = blockIdx.x * 256 + threadIdx.x;   // 64 bh * 64 kb * 64 d
    int bh = i >> 12;
    int kb = (i >> 6) & 63;
    int d  = i & 63;
    const float* vp = V + ((size_t)(bh * NS + kb * 16)) * ND + d;
    unsigned short* op = Vt + ((size_t)(bh * ND + d)) * NS + kb * 16;
    u16x8 o0, o1;
#pragma unroll
    for (int r = 0; r < 8; ++r) o0[r] = __builtin_bit_cast(unsigned short, (__bf16)vp[r * ND]);
#pragma unroll
    for (int r = 0; r < 8; ++r) o1[r] = __builtin_bit_cast(unsigned short, (__bf16)vp[(r + 8) * ND]);
    *(u16x8*)op = o0;
    *(u16x8*)(op + 8) = o1;
}

// ---------------- main fused kernel ----------------
// 256 thr = 4 waves; one (b,h) + 16-query tile; wave w owns keys [w*256, w*256+256).
// Swapped QK^T: mfma(A=K, B=Q) -> lane holds (query = lane&15, keys = (lane>>4)*4 + r).
// __launch_bounds__(256,2): allow up to 256 VGPR — round-2's 88-VGPR build spilled acc[16]
// to scratch (counter evidence: +133 MB WRITE, +170 MB FETCH vs ideal).
__global__ __launch_bounds__(256, 2) void fused_attn_pre(
    const unsigned short* __restrict__ Qhi, const unsigned short* __restrict__ Qlo,
    const unsigned short* __restrict__ Khi, const unsigned short* __restrict__ Klo,
    const unsigned short* __restrict__ Vt,
    const int* __restrict__ mask, const float* __restrict__ adj, const float* __restrict__ dist,
    float* __restrict__ out_g, float* __restrict__ attn_g)
{
    const int tid  = (int)threadIdx.x;
    const int lane = tid & 63;
    const int wid  = tid >> 6;
    const int qi   = lane & 15;
    const int g    = lane >> 4;
    const int l31  = lane & 31;
    const int rhalf = lane >> 5;

    int bid = (int)blockIdx.x;
    bid = (bid & 7) * (NBH * 64 / 8) + (bid >> 3);   // XCD swizzle (bijective: 4096 % 8 == 0)
    const int qt = bid & 63;
    const int bh = bid >> 6;
    const int b  = bh >> 4;

    // LDS: 4 x 8KB per-wave regions, used in sequence as (a) f32 attn store-stage,
    // (b) bf16 P tiles, then unioned as outp for the k-split reduction.
    __shared__ __align__(16) unsigned char smem[4 * 8192 + 512];
    unsigned short* Plds = (unsigned short*)smem;
    float* red_m = (float*)(smem + 32768);          // [4][16]
    float* red_l = red_m + 64;                      // [4][16]
    typedef float outp_t[16][68];                   // +4 pad
    outp_t* outp = (outp_t*)smem;                   // union

    const int qglob = qt * 16 + qi;
    const int kw    = wid * 256;

    // ---- Q fragments (pre-scaled by 1/8 in conv pass)
    bf16x8 qh[2], ql[2];
    {
        const size_t qo = ((size_t)(bh * NS + qglob)) * ND + g * 8;
        qh[0] = __builtin_bit_cast(bf16x8, *(const u16x8*)(Qhi + qo));
        qh[1] = __builtin_bit_cast(bf16x8, *(const u16x8*)(Qhi + qo + 32));
        ql[0] = __builtin_bit_cast(bf16x8, *(const u16x8*)(Qlo + qo));
        ql[1] = __builtin_bit_cast(bf16x8, *(const u16x8*)(Qlo + qo + 32));
    }

    const float* adjR  = adj  + ((size_t)(b * NS + qglob)) * NS;
    const float* distR = dist + ((size_t)(b * NS + qglob)) * NS;
    const int*   maskR = mask + b * NS;
    const float  CE = 3.7182817f;  // 1 + e

    // ---- merged QK^T (hi/lo, 6 MFMA per 16-key tile) + elementwise
    f32x4 acc[16];
#pragma unroll
    for (int t = 0; t < 16; ++t) {
        const size_t ko = ((size_t)(bh * NS + kw + t * 16 + qi)) * ND + g * 8;
        const bf16x8 kh0 = __builtin_bit_cast(bf16x8, *(const u16x8*)(Khi + ko));
        const bf16x8 kl0 = __builtin_bit_cast(bf16x8, *(const u16x8*)(Klo + ko));
        const bf16x8 kh1 = __builtin_bit_cast(bf16x8, *(const u16x8*)(Khi + ko + 32));
        const bf16x8 kl1 = __builtin_bit_cast(bf16x8, *(const u16x8*)(Klo + ko + 32));

        const int k0 = kw + t * 16 + g * 4;
        const f32x4 a4 = *(const f32x4*)(adjR + k0);
        const f32x4 d4 = *(const f32x4*)(distR + k0);
        const int4  m4 = *(const int4*)(maskR + k0);

        f32x4 s = {0.f, 0.f, 0.f, 0.f};
        s = __builtin_amdgcn_mfma_f32_16x16x32_bf16(kh0, qh[0], s, 0, 0, 0);
        s = __builtin_amdgcn_mfma_f32_16x16x32_bf16(kl0, qh[0], s, 0, 0, 0);
        s = __builtin_amdgcn_mfma_f32_16x16x32_bf16(kh0, ql[0], s, 0, 0, 0);
        s = __builtin_amdgcn_mfma_f32_16x16x32_bf16(kh1, qh[1], s, 0, 0, 0);
        s = __builtin_amdgcn_mfma_f32_16x16x32_bf16(kl1, qh[1], s, 0, 0, 0);
        s = __builtin_amdgcn_mfma_f32_16x16x32_bf16(kh1, ql[1], s, 0, 0, 0);

        const int mm[4] = {m4.x, m4.y, m4.z, m4.w};
#pragma unroll
        for (int r = 0; r < 4; ++r) {
            float x = fmaxf(s[r], 0.f);
            float resc = CE * __builtin_amdgcn_rcpf(1.f + __expf(1.f - d4[r]));
            x = x * resc + a4[r];
            acc[t][r] = (mm[r] == 0) ? -1.0e9f : x;
        }
    }

    // ---- softmax over the full 1024-key row
    float m = -3.0e38f;
#pragma unroll
    for (int t = 0; t < 16; ++t)
#pragma unroll
        for (int r = 0; r < 4; ++r) m = fmaxf(m, acc[t][r]);
    m = fmaxf(m, __shfl_xor(m, 16, 64));
    m = fmaxf(m, __shfl_xor(m, 32, 64));
    if (g == 0) red_m[wid * 16 + qi] = m;
    __syncthreads();
    const float mf = fmaxf(fmaxf(red_m[qi], red_m[16 + qi]),
                           fmaxf(red_m[32 + qi], red_m[48 + qi]));

    float l = 0.f;
#pragma unroll
    for (int t = 0; t < 16; ++t)
#pragma unroll
        for (int r = 0; r < 4; ++r) {
            float e = __expf(acc[t][r] - mf);
            acc[t][r] = e;
            l += e;
        }
    l += __shfl_xor(l, 16, 64);
    l += __shfl_xor(l, 32, 64);
    if (g == 0) red_l[wid * 16 + qi] = l;
    __syncthreads();
    const float lf = red_l[qi] + red_l[16 + qi] + red_l[32 + qi] + red_l[48 + qi];
    const float inv = __builtin_amdgcn_rcpf(lf);

    // ---- attn store via LDS round-trip: 2 rows x 512B contiguous per instruction
    // (full 128B lines -> no partial-line/RFO write amplification)
    float* stage = (float*)(smem + (size_t)wid * 8192);   // [16 rows][128 f32], chunk-swizzled
    float* attnRow0 = attn_g + ((size_t)(bh * NS + qt * 16)) * NS + kw;
#pragma unroll
    for (int h = 0; h < 2; ++h) {
        __syncthreads();
#pragma unroll
        for (int tl = 0; tl < 8; ++tl) {
            const int t = h * 8 + tl;
            f32x4 e4;
#pragma unroll
            for (int r = 0; r < 4; ++r) e4[r] = acc[t][r] * inv;
            const int chunk = (tl * 4 + g) ^ (qi & 7);    // 16B-chunk XOR swizzle
            *(f32x4*)((char*)stage + qi * 512 + chunk * 16) = e4;
        }
        __syncthreads();
#pragma unroll
        for (int i = 0; i < 8; ++i) {
            const int r = i * 2 + rhalf;
            const int chunk = l31 ^ (r & 7);
            f32x4 v = *(const f32x4*)((const char*)stage + r * 512 + chunk * 16);
            __builtin_nontemporal_store(v, (f32x4*)(attnRow0 + (size_t)r * NS + h * 128 + l31 * 4));
        }
    }
    __syncthreads();

    // ---- pack P to LDS (bf16, 16B-chunk XOR swizzle) for PV
    unsigned short* Pw = Plds + wid * (16 * 256);
#pragma unroll
    for (int t = 0; t < 16; ++t) {
        const int kloc = t * 16 + g * 4;
        unsigned int p01 = ((unsigned int)__builtin_bit_cast(unsigned short, (__bf16)(acc[t][0] * inv)))
                         | ((unsigned int)__builtin_bit_cast(unsigned short, (__bf16)(acc[t][1] * inv)) << 16);
        unsigned int p23 = ((unsigned int)__builtin_bit_cast(unsigned short, (__bf16)(acc[t][2] * inv)))
                         | ((unsigned int)__builtin_bit_cast(unsigned short, (__bf16)(acc[t][3] * inv)) << 16);
        const int u = kloc >> 2;          // 8B unit within row
        const int c = u >> 1;             // 16B chunk 0..31
        unsigned long long pk = (unsigned long long)p01 | ((unsigned long long)p23 << 32);
        *(unsigned long long*)((char*)Pw + qi * 512 + ((c ^ (qi & 7)) << 4) + (u & 1) * 8) = pk;
    }
    __syncthreads();

    // ---- PV: A = P (LDS), B = V^T (b128 global loads, L2-resident)
    f32x4 o[4];
    {
        const f32x4 z = {0.f, 0.f, 0.f, 0.f};
#pragma unroll
        for (int dt = 0; dt < 4; ++dt) o[dt] = z;
    }
    const unsigned short* vtb = Vt + ((size_t)bh * ND) * NS;
#pragma unroll
    for (int j = 0; j < 8; ++j) {                 // 32-key chunks
        const int c = j * 4 + g;
        const u16x8 praw = *(const u16x8*)((const char*)Pw + qi * 512 + ((c ^ (qi & 7)) << 4));
        const bf16x8 pa = __builtin_bit_cast(bf16x8, praw);
#pragma unroll
        for (int dt = 0; dt < 4; ++dt) {          // 16-wide d tiles
            const bf16x8 vb = __builtin_bit_cast(bf16x8,
                *(const u16x8*)(vtb + (size_t)(dt * 16 + qi) * NS + kw + j * 32 + g * 8));
            o[dt] = __builtin_amdgcn_mfma_f32_16x16x32_bf16(pa, vb, o[dt], 0, 0, 0);
        }
    }
    __syncthreads();   // P dead; outp (union) comes live

    // ---- cross-wave reduce of k-split partials, store out (256B/row, full lines)
#pragma unroll
    for (int dt = 0; dt < 4; ++dt)
#pragma unroll
        for (int r = 0; r < 4; ++r)
            outp[wid][g * 4 + r][dt * 16 + qi] = o[dt][r];
    __syncthreads();
    {
        const int qrow = tid >> 4;
        const int d0   = (tid & 15) * 4;
        f32x4 s = *(const f32x4*)(&outp[0][qrow][d0]);
#pragma unroll
        for (int w = 1; w < 4; ++w) s += *(const f32x4*)(&outp[w][qrow][d0]);
        __builtin_nontemporal_store(s, (f32x4*)(out_g + ((size_t)(bh * NS + qt * 16 + qrow)) * ND + d0));
    }
}

// ---------------- fallback (self-contained, used only if ws too small) ----------------
__global__ __launch_bounds__(256, 2) void fused_attn_kernel(
    const float* __restrict__ Q, const float* __restrict__ K, const float* __restrict__ V,
    const int* __restrict__ mask, const float* __restrict__ adj, const float* __restrict__ dist,
    float* __restrict__ out_g, float* __restrict__ attn_g)
{
    const int tid  = (int)threadIdx.x;
    const int lane = tid & 63;
    const int wid  = tid >> 6;
    const int qi   = lane & 15;
    const int g    = lane >> 4;

    const int bid = (int)blockIdx.x;
    const int qt  = bid & 63;
    const int bh  = bid >> 6;
    const int b   = bh >> 4;

    __shared__ __align__(16) unsigned short Plds[4][16 * 256];
    __shared__ __align__(16) float outp[4][16][68];
    __shared__ float red_m[4][16];
    __shared__ float red_l[4][16];

    const int qglob = qt * 16 + qi;
    const int kw    = wid * 256;

    bf16x8 qh[2], ql[2];
    {
        const float* qp = Q + (bh * NS + qglob) * ND + g * 8;
#pragma unroll
        for (int c = 0; c < 2; ++c) {
            f32x4 f0 = *(const f32x4*)(qp + c * 32);
            f32x4 f1 = *(const f32x4*)(qp + c * 32 + 4);
#pragma unroll
            for (int j = 0; j < 4; ++j) {
                float xh = f0[j] * 0.125f;
                __bf16 hb = (__bf16)xh;
                qh[c][j] = hb; ql[c][j] = (__bf16)(xh - (float)hb);
                float xl = f1[j] * 0.125f;
                __bf16 hb2 = (__bf16)xl;
                qh[c][j + 4] = hb2; ql[c][j + 4] = (__bf16)(xl - (float)hb2);
            }
        }
    }

    f32x4 acc[16];
#pragma unroll
    for (int t = 0; t < 16; ++t) {
        const float* kp = K + (bh * NS + kw + t * 16 + qi) * ND + g * 8;
        f32x4 s = {0.f, 0.f, 0.f, 0.f};
#pragma unroll
        for (int c = 0; c < 2; ++c) {
            f32x4 f0 = *(const f32x4*)(kp + c * 32);
            f32x4 f1 = *(const f32x4*)(kp + c * 32 + 4);
            bf16x8 kh, kl;
#pragma unroll
            for (int j = 0; j < 4; ++j) {
                __bf16 hb = (__bf16)f0[j];
                kh[j] = hb; kl[j] = (__bf16)(f0[j] - (float)hb);
                __bf16 hb2 = (__bf16)f1[j];
                kh[j + 4] = hb2; kl[j + 4] = (__bf16)(f1[j] - (float)hb2);
            }
            s = __builtin_amdgcn_mfma_f32_16x16x32_bf16(kh, qh[c], s, 0, 0, 0);
            s = __builtin_amdgcn_mfma_f32_16x16x32_bf16(kl, qh[c], s, 0, 0, 0);
            s = __builtin_amdgcn_mfma_f32_16x16x32_bf16(kh, ql[c], s, 0, 0, 0);
        }
        acc[t] = s;
    }

    const float* adjR  = adj  + (b * NS + qglob) * (size_t)NS;
    const float* distR = dist + (b * NS + qglob) * (size_t)NS;
    const int*   maskR = mask + b * NS;
    const float  CE = 3.7182817f;

#pragma unroll
    for (int t = 0; t < 16; ++t) {
        const int k0 = kw + t * 16 + g * 4;
        f32x4 a4 = *(const f32x4*)(adjR + k0);
        f32x4 d4 = *(const f32x4*)(distR + k0);
        int4  m4 = *(const int4*)(maskR + k0);
        int   mm[4] = {m4.x, m4.y, m4.z, m4.w};
#pragma unroll
        for (int r = 0; r < 4; ++r) {
            float s = fmaxf(acc[t][r], 0.f);
            float resc = CE * __builtin_amdgcn_rcpf(1.f + __expf(1.f - d4[r]));
            s = s * resc + a4[r];
            acc[t][r] = (mm[r] == 0) ? -1.0e9f : s;
        }
    }

    float m = -3.0e38f;
#pragma unroll
    for (int t = 0; t < 16; ++t)
#pragma unroll
        for (int r = 0; r < 4; ++r) m = fmaxf(m, acc[t][r]);
    m = fmaxf(m, __shfl_xor(m, 16, 64));
    m = fmaxf(m, __shfl_xor(m, 32, 64));
    if (g == 0) red_m[wid][qi] = m;
    __syncthreads();
    const float mf = fmaxf(fmaxf(red_m[0][qi], red_m[1][qi]),
                           fmaxf(red_m[2][qi], red_m[3][qi]));

    float l = 0.f;
#pragma unroll
    for (int t = 0; t < 16; ++t)
#pragma unroll
        for (int r = 0; r < 4; ++r) {
            float e = __expf(acc[t][r] - mf);
            acc[t][r] = e;
            l += e;
        }
    l += __shfl_xor(l, 16, 64);
    l += __shfl_xor(l, 32, 64);
    if (g == 0) red_l[wid][qi] = l;
    __syncthreads();
    const float lf = red_l[0][qi] + red_l[1][qi] + red_l[2][qi] + red_l[3][qi];
    const float inv = __builtin_amdgcn_rcpf(lf);

    float* attnR = attn_g + (bh * NS + qglob) * (size_t)NS;
    unsigned short* Pw = &Plds[wid][0];
#pragma unroll
    for (int t = 0; t < 16; ++t) {
        const int kloc = t * 16 + g * 4;
        f32x4 e4;
#pragma unroll
        for (int r = 0; r < 4; ++r) e4[r] = acc[t][r] * inv;
        __builtin_nontemporal_store(e4, (f32x4*)(attnR + kw + kloc));

        unsigned int p01 = ((unsigned int)__builtin_bit_cast(unsigned short, (__bf16)e4[0]))
                         | ((unsigned int)__builtin_bit_cast(unsigned short, (__bf16)e4[1]) << 16);
        unsigned int p23 = ((unsigned int)__builtin_bit_cast(unsigned short, (__bf16)e4[2]))
                         | ((unsigned int)__builtin_bit_cast(unsigned short, (__bf16)e4[3]) << 16);
        const int u = kloc >> 2;
        const int c = u >> 1;
        unsigned long long pk = (unsigned long long)p01 | ((unsigned long long)p23 << 32);
        *(unsigned long long*)((char*)Pw + qi * 512 + ((c ^ (qi & 7)) << 4) + (u & 1) * 8) = pk;
    }
    __syncthreads();

    f32x4 o[4];
    {
        const f32x4 z = {0.f, 0.f, 0.f, 0.f};
#pragma unroll
        for (int dt = 0; dt < 4; ++dt) o[dt] = z;
    }
    const float* vbase = V + (bh * NS + kw) * (size_t)ND;
#pragma unroll
    for (int j = 0; j < 8; ++j) {
        const int c = j * 4 + g;
        const u16x8 praw = *(const u16x8*)((const char*)Pw + qi * 512 + ((c ^ (qi & 7)) << 4));
        const bf16x8 pa = __builtin_bit_cast(bf16x8, praw);
        const float* vp0 = vbase + (j * 32 + g * 8) * ND + qi;
#pragma unroll
        for (int dt = 0; dt < 4; ++dt) {
            bf16x8 vb;
            const float* vp = vp0 + dt * 16;
#pragma unroll
            for (int r = 0; r < 8; ++r) vb[r] = (__bf16)vp[r * ND];
            o[dt] = __builtin_amdgcn_mfma_f32_16x16x32_bf16(pa, vb, o[dt], 0, 0, 0);
        }
    }

#pragma unroll
    for (int dt = 0; dt < 4; ++dt)
#pragma unroll
        for (int r = 0; r < 4; ++r)
            outp[wid][g * 4 + r][dt * 16 + qi] = o[dt][r];
    __syncthreads();
    {
        const int qrow = tid >> 4;
        const int d0   = (tid & 15) * 4;
        f32x4 s = *(const f32x4*)(&outp[0][qrow][d0]);
#pragma unroll
        for (int w = 1; w < 4; ++w) s += *(const f32x4*)(&outp[w][qrow][d0]);
        __builtin_nontemporal_store(s, (f32x4*)(out_g + (bh * NS + qt * 16 + qrow) * (size_t)ND + d0));
    }
}

extern "C" void kernel_launch(void* const* d_in, const int* in_sizes, int n_in,
                              void* d_out, int out_size, void* d_ws, size_t ws_size,
                              hipStream_t stream) {
    const float* Q    = (const float*)d_in[0];
    const float* K    = (const float*)d_in[1];
    const float* V    = (const float*)d_in[2];
    const int*   mask = (const int*)d_in[3];
    const float* adj  = (const float*)d_in[4];
    const float* dist = (const float*)d_in[5];
    float* out  = (float*)d_out;
    float* attn = out + NELEM;   // outputs concatenated: (output, attn)

    const size_t need = NELEM * 2 * 5;   // Qhi,Qlo,Khi,Klo,Vt bf16 planes = 40 MB
    if (ws_size >= need) {
        unsigned short* Qhi = (unsigned short*)d_ws;
        unsigned short* Qlo = Qhi + NELEM;
        unsigned short* Khi = Qlo + NELEM;
        unsigned short* Klo = Khi + NELEM;
        unsigned short* Vt  = Klo + NELEM;
        const int n4 = (int)(NELEM / 4);
        conv_hilo<<<dim3(n4 / 256), 256, 0, stream>>>(Q, Qhi, Qlo, 0.125f, n4);
        conv_hilo<<<dim3(n4 / 256), 256, 0, stream>>>(K, Khi, Klo, 1.0f, n4);
        conv_vt<<<dim3(NBH * ND * (NS / 16) / 256), 256, 0, stream>>>(V, Vt);
        fused_attn_pre<<<dim3(NBH * 64), 256, 0, stream>>>(Qhi, Qlo, Khi, Klo, Vt,
                                                           mask, adj, dist, out, attn);
    } else {
        fused_attn_kernel<<<dim3(NBH * 64), 256, 0, stream>>>(Q, K, V, mask, adj, dist, out, attn);
    }
}